// Round 5
// baseline (86.816 us; speedup 1.0000x reference)
//
#include <hip/hip_runtime.h>
#include <hip/hip_cooperative_groups.h>
#include <math.h>

namespace cg = cooperative_groups;

#define H 512
#define W 512
#define PH 256   // maxpool output dims (k3, s2, p1)
#define PW 256
#define OH 128   // unfold output dims (k5, s4, p1)
#define OW 128
#define NPLANES 96           // 32 * 3

__device__ __forceinline__ float4 fmax4(float4 a, float4 b) {
    return make_float4(fmaxf(a.x, b.x), fmaxf(a.y, b.y),
                       fmaxf(a.z, b.z), fmaxf(a.w, b.w));
}
__device__ __forceinline__ float4 fadd4(float4 a, float4 b) {
    return make_float4(a.x + b.x, a.y + b.y, a.z + b.z, a.w + b.w);
}
__device__ __forceinline__ float hsum4(float4 a) {
    return a.x + a.y + a.z + a.w;
}

// ---------------- cooperative single-pass kernel ----------------
// 96 planes * 4 blocks = 384 blocks (1.5/CU -> co-residency guaranteed).
// Each block = 4 waves; each wave handles 4 t-tiles (8 input rows + halo).
// Phase 1: maxpool(3x3,s2,p1) partial sums -> ws[], 5x5/s4/p1 window sums
//          kept in registers (oo[4][2]).
// grid.sync()
// Phase 2: gate from 4 per-plane partials, scale registers, write out.
#define C_BPP 4
#define C_NBLOCKS (NPLANES * C_BPP)   // 384

__global__ __launch_bounds__(256, 2) void fused_all(
    const float* __restrict__ x, float* __restrict__ ws,
    float* __restrict__ out) {
    // XCD-chunked swizzle (384 % 8 == 0 -> bijective): each XCD gets 12
    // whole planes, so halos + partials stay L2-local.
    const int n = blockIdx.x;
    const int bx = (n & 7) * (C_NBLOCKS / 8) + (n >> 3);
    const int plane = bx / C_BPP;
    const int sub = bx % C_BPP;
    const float* __restrict__ p = x + (size_t)plane * (H * W);
    const int wid = threadIdx.x >> 6;
    const int lane = threadIdx.x & 63;
    const int col = lane << 3;

    float acc = 0.f;          // maxpool partial
    float2 oo[4][2];          // [tile u][row r] = (ow=2l, ow=2l+1) sums

    #pragma unroll
    for (int u = 0; u < 4; ++u) {
        const int t = sub * 16 + wid * 4 + u;   // 0..63
        // load 9 rows (8t-1 .. 8t+7); row -1 clamped to 0
        float4 a[9], b[9];
        #pragma unroll
        for (int j = 0; j < 9; ++j) {
            int r = 8 * t - 1 + j;
            if (r < 0) r = 0;
            const float* rp = p + r * W + col;
            a[j] = *(const float4*)(rp);
            b[j] = *(const float4*)(rp + 4);
        }

        // maxpool partial (pooled rows 4t..4t+3); clamp-dup is max-safe
        #pragma unroll
        for (int k = 0; k < 4; ++k) {
            float4 va = fmax4(fmax4(a[2 * k], a[2 * k + 1]), a[2 * k + 2]);
            float4 vb = fmax4(fmax4(b[2 * k], b[2 * k + 1]), b[2 * k + 2]);
            float vL = __shfl_up(vb.w, 1, 64);
            if (lane == 0) vL = va.x;
            acc += fmaxf(fmaxf(vL, va.x), va.y);
            acc += fmaxf(fmaxf(va.y, va.z), va.w);
            acc += fmaxf(fmaxf(va.w, vb.x), vb.y);
            acc += fmaxf(fmaxf(vb.y, vb.z), vb.w);
        }

        // 5x5 window sums, out rows 2t (a[0..4]) and 2t+1 (a[4..8]);
        // j=0 is the zero-pad row when t==0
        float4 z = make_float4(0.f, 0.f, 0.f, 0.f);
        float4 a0 = (t == 0) ? z : a[0];
        float4 b0 = (t == 0) ? z : b[0];
        float4 sa0 = fadd4(fadd4(fadd4(a0, a[1]), fadd4(a[2], a[3])), a[4]);
        float4 sb0 = fadd4(fadd4(fadd4(b0, b[1]), fadd4(b[2], b[3])), b[4]);
        float4 sa1 = fadd4(fadd4(fadd4(a[4], a[5]), fadd4(a[6], a[7])), a[8]);
        float4 sb1 = fadd4(fadd4(fadd4(b[4], b[5]), fadd4(b[6], b[7])), b[8]);

        float sL0 = __shfl_up(sb0.w, 1, 64);
        float sL1 = __shfl_up(sb1.w, 1, 64);
        if (lane == 0) { sL0 = 0.f; sL1 = 0.f; }   // zero pad col -1
        oo[u][0] = make_float2(sL0 + hsum4(sa0), sa0.w + hsum4(sb0));
        oo[u][1] = make_float2(sL1 + hsum4(sa1), sa1.w + hsum4(sb1));
    }

    // block-reduce maxpool partial -> ws[bx]
    #pragma unroll
    for (int off = 32; off > 0; off >>= 1)
        acc += __shfl_down(acc, off, 64);
    __shared__ float smem[4];
    if (lane == 0) smem[wid] = acc;
    __syncthreads();
    if (threadIdx.x == 0)
        ws[plane * C_BPP + sub] = smem[0] + smem[1] + smem[2] + smem[3];

    cg::this_grid().sync();

    // gate: 4 lanes each load one partial, butterfly-sum
    float s = ws[plane * C_BPP + (lane & 3)];
    s += __shfl_xor(s, 1, 64);
    s += __shfl_xor(s, 2, 64);
    s *= (1.0f / (float)(PH * PW));
    const float gate = s / (1.0f + expf(-s));
    const float scale = gate * (1.0f / 25.0f);

    float* oplane = out + (size_t)plane * (OH * OW);
    #pragma unroll
    for (int u = 0; u < 4; ++u) {
        const int t = sub * 16 + wid * 4 + u;
        #pragma unroll
        for (int r = 0; r < 2; ++r) {
            float2 v = oo[u][r];
            *(float2*)&oplane[(size_t)(2 * t + r) * OW + 2 * lane] =
                make_float2(v.x * scale, v.y * scale);
        }
    }
}

// ---------------- fallback: proven R3 two-kernel path ----------------
#define F_TPP 16           // fallback blocks per plane
#define WS_PARTIALS 0
#define WS_WSUM 2048

__global__ __launch_bounds__(256, 4) void fused_kernel(
    const float* __restrict__ x, float* __restrict__ ws) {
    const int bx = blockIdx.x;
    const int plane = bx / F_TPP;
    const int sub = bx % F_TPP;
    const float* __restrict__ p = x + (size_t)plane * (H * W);
    const int wid = threadIdx.x >> 6;
    const int lane = threadIdx.x & 63;
    const int t = sub * 4 + wid;
    const int col = lane << 3;

    float4 a[9], b[9];
    #pragma unroll
    for (int j = 0; j < 9; ++j) {
        int r = 8 * t - 1 + j;
        if (r < 0) r = 0;
        const float* rp = p + r * W + col;
        a[j] = *(const float4*)(rp);
        b[j] = *(const float4*)(rp + 4);
    }

    float acc = 0.f;
    #pragma unroll
    for (int k = 0; k < 4; ++k) {
        float4 va = fmax4(fmax4(a[2 * k], a[2 * k + 1]), a[2 * k + 2]);
        float4 vb = fmax4(fmax4(b[2 * k], b[2 * k + 1]), b[2 * k + 2]);
        float vL = __shfl_up(vb.w, 1, 64);
        if (lane == 0) vL = va.x;
        acc += fmaxf(fmaxf(vL, va.x), va.y);
        acc += fmaxf(fmaxf(va.y, va.z), va.w);
        acc += fmaxf(fmaxf(va.w, vb.x), vb.y);
        acc += fmaxf(fmaxf(vb.y, vb.z), vb.w);
    }
    #pragma unroll
    for (int off = 32; off > 0; off >>= 1)
        acc += __shfl_down(acc, off, 64);
    __shared__ float smem[4];
    if (lane == 0) smem[wid] = acc;

    float4 z = make_float4(0.f, 0.f, 0.f, 0.f);
    float4 a0 = (t == 0) ? z : a[0];
    float4 b0 = (t == 0) ? z : b[0];
    float4 sa0 = fadd4(fadd4(fadd4(a0, a[1]), fadd4(a[2], a[3])), a[4]);
    float4 sb0 = fadd4(fadd4(fadd4(b0, b[1]), fadd4(b[2], b[3])), b[4]);
    float4 sa1 = fadd4(fadd4(fadd4(a[4], a[5]), fadd4(a[6], a[7])), a[8]);
    float4 sb1 = fadd4(fadd4(fadd4(b[4], b[5]), fadd4(b[6], b[7])), b[8]);

    float* wrow = ws + WS_WSUM + (size_t)plane * (OH * OW);
    {
        float sL = __shfl_up(sb0.w, 1, 64);
        if (lane == 0) sL = 0.f;
        *(float2*)&wrow[(2 * t) * OW + 2 * lane] =
            make_float2(sL + hsum4(sa0), sa0.w + hsum4(sb0));
    }
    {
        float sL = __shfl_up(sb1.w, 1, 64);
        if (lane == 0) sL = 0.f;
        *(float2*)&wrow[(2 * t + 1) * OW + 2 * lane] =
            make_float2(sL + hsum4(sa1), sa1.w + hsum4(sb1));
    }

    __syncthreads();
    if (threadIdx.x == 0)
        ws[WS_PARTIALS + plane * F_TPP + sub] =
            smem[0] + smem[1] + smem[2] + smem[3];
}

__global__ __launch_bounds__(256) void scale_kernel(
    const float* __restrict__ ws, float* __restrict__ out) {
    const int bx = blockIdx.x;
    const int plane = bx >> 2;
    const int quarter = bx & 3;

    float s = 0.f;
    #pragma unroll
    for (int i = 0; i < F_TPP; ++i)
        s += ws[WS_PARTIALS + plane * F_TPP + i];
    s *= (1.0f / (float)(PH * PW));
    const float gate = s / (1.0f + expf(-s));
    const float scale = gate * (1.0f / 25.0f);

    const float4* src = (const float4*)(ws + WS_WSUM + (size_t)plane * (OH * OW));
    float4* dst = (float4*)(out + (size_t)plane * (OH * OW));
    const int base = quarter * 1024 + threadIdx.x;
    #pragma unroll
    for (int i = 0; i < 4; ++i) {
        const int idx = base + i * 256;
        float4 v = src[idx];
        dst[idx] = make_float4(v.x * scale, v.y * scale,
                               v.z * scale, v.w * scale);
    }
}

extern "C" void kernel_launch(void* const* d_in, const int* in_sizes, int n_in,
                              void* d_out, int out_size, void* d_ws, size_t ws_size,
                              hipStream_t stream) {
    const float* x = (const float*)d_in[0];
    float* out = (float*)d_out;
    float* ws = (float*)d_ws;

    void* args[] = {(void*)&x, (void*)&ws, (void*)&out};
    hipError_t err = hipLaunchCooperativeKernel(
        (const void*)fused_all, dim3(C_NBLOCKS), dim3(256), args, 0, stream);
    if (err != hipSuccess) {
        (void)hipGetLastError();   // clear sticky error
        fused_kernel<<<NPLANES * F_TPP, 256, 0, stream>>>(x, ws);
        scale_kernel<<<NPLANES * 4, 256, 0, stream>>>(ws, out);
    }
}